// Round 1
// baseline (1108.259 us; speedup 1.0000x reference)
//
#include <hip/hip_runtime.h>
#include <cstdint>

// ---- problem constants ----
constexpr int B_       = 8;
constexpr int NPG_     = 12500;    // nodes per graph
constexpr int KSEL_    = 64;       // sort-pool k
constexpr int TOTAL_N_ = 100000;
constexpr int TOTAL_E_ = 1600000;
constexpr int NKEY_    = 16384;    // padded per-graph key count (pow2 >= NPG_)
constexpr int NB_SCAN  = (TOTAL_N_ + 255) / 256;   // 391
constexpr int OUT_ROW  = KSEL_ * (128 + 32);       // 10240

__device__ __forceinline__ float lrelu(float v){ return v >= 0.f ? v : 0.01f * v; }

// ---------------- degrees ----------------
__global__ void deg_kernel(const int* __restrict__ src, const int* __restrict__ dst,
                           int* __restrict__ out_cnt, int* __restrict__ in_cnt){
  int i = blockIdx.x * 256 + threadIdx.x;
  if (i < TOTAL_E_){
    atomicAdd(&out_cnt[src[i]], 1);
    atomicAdd(&in_cnt[dst[i]], 1);
  }
}

__global__ void rsq_kernel(const int* __restrict__ in_cnt, const int* __restrict__ out_cnt,
                           float* __restrict__ rsq_in, float* __restrict__ rsq_out){
  int i = blockIdx.x * 256 + threadIdx.x;
  if (i < TOTAL_N_){
    int ic = in_cnt[i];  if (ic < 1) ic = 1;
    int oc = out_cnt[i]; if (oc < 1) oc = 1;
    rsq_in[i]  = rsqrtf((float)ic);
    rsq_out[i] = rsqrtf((float)oc);
  }
}

// ---------------- exclusive scan (3 kernels) ----------------
__global__ void scan_blocks(const int* __restrict__ cnt, int* __restrict__ off, int* __restrict__ bsum){
  __shared__ int tmp[256];
  int t = threadIdx.x;
  int i = blockIdx.x * 256 + t;
  int x = (i < TOTAL_N_) ? cnt[i] : 0;
  tmp[t] = x;
  __syncthreads();
  for (int d = 1; d < 256; d <<= 1){
    int v = (t >= d) ? tmp[t - d] : 0;
    __syncthreads();
    tmp[t] += v;
    __syncthreads();
  }
  if (i < TOTAL_N_) off[i] = tmp[t] - x;     // exclusive within block
  if (t == 255) bsum[blockIdx.x] = tmp[255];
}

__global__ void scan_sums(int* __restrict__ bsum, int nb){
  __shared__ int tmp[512];
  int t = threadIdx.x;
  int x = (t < nb) ? bsum[t] : 0;
  tmp[t] = x;
  __syncthreads();
  for (int d = 1; d < 512; d <<= 1){
    int v = (t >= d) ? tmp[t - d] : 0;
    __syncthreads();
    tmp[t] += v;
    __syncthreads();
  }
  if (t < nb) bsum[t] = tmp[t] - x;          // exclusive block offsets
}

__global__ void scan_add(int* __restrict__ off, const int* __restrict__ bsum){
  int i = blockIdx.x * 256 + threadIdx.x;
  if (i < TOTAL_N_) off[i] += bsum[blockIdx.x];
}

// ---------------- CSR fill (bucket by dst) ----------------
__global__ void fill_csr(const int* __restrict__ src, const int* __restrict__ dst,
                         const float* __restrict__ ew, const int* __restrict__ off,
                         int* __restrict__ cursor, int* __restrict__ csr_src, float* __restrict__ csr_w){
  int i = blockIdx.x * 256 + threadIdx.x;
  if (i < TOTAL_E_){
    int d = dst[i];
    int p = atomicAdd(&cursor[d], 1);
    int slot = off[d] + p;
    csr_src[slot] = src[i];
    csr_w[slot]   = ew[i];
  }
}

// ---------------- layer 1: SpMM in 64-d input space ----------------
// agg[v][c] = sum_e csr_w * rsq_out[src] * feat[src][c]
__global__ void spmm1(const int* __restrict__ off, const int* __restrict__ cnt,
                      const int* __restrict__ csr_src, const float* __restrict__ csr_w,
                      const float* __restrict__ rsq_out, const float* __restrict__ feat,
                      float* __restrict__ agg){
  int wid  = (blockIdx.x * 256 + threadIdx.x) >> 6;   // one node per wave
  int lane = threadIdx.x & 63;
  if (wid >= TOTAL_N_) return;
  int s0 = off[wid];
  int n  = cnt[wid];
  float acc = 0.f;
  int e = 0;
  for (; e + 1 < n; e += 2){
    int sA = csr_src[s0 + e], sB = csr_src[s0 + e + 1];
    float wA = csr_w[s0 + e]     * rsq_out[sA];
    float wB = csr_w[s0 + e + 1] * rsq_out[sB];
    acc += wA * feat[(size_t)sA * 64 + lane];
    acc += wB * feat[(size_t)sB * 64 + lane];
  }
  if (e < n){
    int sA = csr_src[s0 + e];
    acc += csr_w[s0 + e] * rsq_out[sA] * feat[(size_t)sA * 64 + lane];
  }
  agg[(size_t)wid * 64 + lane] = acc;
}

// h1c[n][c] = rsq_in[n] * dot(agg[n][0:64], W1[:,c])   (W1: [64,128] row-major)
__global__ void proj1(const float* __restrict__ agg, const float* __restrict__ W1,
                      const float* __restrict__ rsq_in, float* __restrict__ h1){
  __shared__ float w[64 * 128];   // 32 KB
  __shared__ float a[32][64];     // 8 KB
  int t = threadIdx.x;            // 256
  for (int i = t; i < 64 * 128; i += 256) w[i] = W1[i];
  int base = blockIdx.x * 32;
  for (int i = t; i < 32 * 64; i += 256){
    int r = i >> 6, c = i & 63;
    a[r][c] = agg[(size_t)(base + r) * 64 + c];
  }
  __syncthreads();
  int c  = t & 127;
  int r0 = t >> 7;                // 0..1
  for (int rr = r0; rr < 32; rr += 2){
    float acc = 0.f;
    #pragma unroll
    for (int k = 0; k < 64; ++k) acc += a[rr][k] * w[k * 128 + c];
    int node = base + rr;
    h1[(size_t)node * 128 + c] = acc * rsq_in[node];
  }
}

// per-(graph,channel) sum & sumsq, D=128
__global__ void stats1(const float* __restrict__ h, float* __restrict__ gsum, float* __restrict__ gsq){
  int b = blockIdx.x / 25, chunk = blockIdx.x % 25;
  int t = threadIdx.x;
  int c = t & 127, r0 = t >> 7;
  size_t base = ((size_t)b * NPG_ + (size_t)chunk * 500) * 128;
  float s = 0.f, q = 0.f;
  for (int r = r0; r < 500; r += 2){
    float v = h[base + (size_t)r * 128 + c];
    s += v; q += v * v;
  }
  __shared__ float ls[256], lq[256];
  ls[t] = s; lq[t] = q;
  __syncthreads();
  if (t < 128){
    s = ls[t] + ls[t + 128];
    q = lq[t] + lq[t + 128];
    atomicAdd(&gsum[b * 128 + c], s);
    atomicAdd(&gsq [b * 128 + c], q);
  }
}

__global__ void finalize1(const float* __restrict__ gsum, const float* __restrict__ gsq,
                          const float* __restrict__ gamma, const float* __restrict__ beta,
                          const float* __restrict__ alpha, float* __restrict__ mul, float* __restrict__ add){
  int i = threadIdx.x;            // 1024 = 8*128
  int c = i & 127;
  const float invn = 1.0f / (float)NPG_;
  float m = gsum[i] * invn;
  float a = alpha[c];
  float var = gsq[i] * invn - 2.f * a * m * m + a * a * m * m;
  float mu = gamma[c] * rsqrtf(var + 1e-5f);
  mul[i] = mu;
  add[i] = beta[c] - mu * a * m;
}

// normalize+leaky in place, emit per-node sort key (max channel, composite desc-value/asc-index)
__global__ void norm1(float* __restrict__ h, const float* __restrict__ mul, const float* __restrict__ add,
                      unsigned long long* __restrict__ keys){
  int wid  = (blockIdx.x * 256 + threadIdx.x) >> 6;
  int lane = threadIdx.x & 63;
  if (wid >= TOTAL_N_) return;
  int b = wid / NPG_;
  int nloc = wid - b * NPG_;
  size_t base = (size_t)wid * 128;
  int c0 = lane, c1 = lane + 64;
  float v0 = h[base + c0], v1 = h[base + c1];
  v0 = lrelu(mul[b * 128 + c0] * v0 + add[b * 128 + c0]);
  v1 = lrelu(mul[b * 128 + c1] * v1 + add[b * 128 + c1]);
  h[base + c0] = v0;
  h[base + c1] = v1;
  float m = fmaxf(v0, v1);
  for (int o = 1; o < 64; o <<= 1) m = fmaxf(m, __shfl_xor(m, o));
  if (lane == 0){
    unsigned u = __float_as_uint(m);
    u ^= (u >> 31) ? 0xFFFFFFFFu : 0x80000000u;   // monotonic ascending map
    unsigned k32 = ~u;                            // descending
    keys[(size_t)b * NKEY_ + nloc] = ((unsigned long long)k32 << 32) | (unsigned)nloc;
  }
}

// ---------------- top-k selection (2-stage bitonic) ----------------
__global__ void topk_s1(const unsigned long long* __restrict__ keys, unsigned long long* __restrict__ cand){
  __shared__ unsigned long long s[2048];
  int b = blockIdx.x >> 3, ch = blockIdx.x & 7;
  int t = threadIdx.x;            // 256
  for (int i = t; i < 2048; i += 256) s[i] = keys[(size_t)b * NKEY_ + (size_t)ch * 2048 + i];
  for (int k2 = 2; k2 <= 2048; k2 <<= 1){
    for (int j = k2 >> 1; j > 0; j >>= 1){
      __syncthreads();
      for (int i = t; i < 2048; i += 256){
        int p = i ^ j;
        if (p > i){
          unsigned long long A = s[i], C = s[p];
          bool up = ((i & k2) == 0);
          if ((A > C) == up){ s[i] = C; s[p] = A; }
        }
      }
    }
  }
  __syncthreads();
  if (t < 64) cand[(size_t)b * 512 + (size_t)ch * 64 + t] = s[t];
}

__global__ void topk_s2(const unsigned long long* __restrict__ cand, int* __restrict__ topidx){
  __shared__ unsigned long long s[512];
  int b = blockIdx.x;
  int t = threadIdx.x;            // 256
  for (int i = t; i < 512; i += 256) s[i] = cand[(size_t)b * 512 + i];
  for (int k2 = 2; k2 <= 512; k2 <<= 1){
    for (int j = k2 >> 1; j > 0; j >>= 1){
      __syncthreads();
      for (int i = t; i < 512; i += 256){
        int p = i ^ j;
        if (p > i){
          unsigned long long A = s[i], C = s[p];
          bool up = ((i & k2) == 0);
          if ((A > C) == up){ s[i] = C; s[p] = A; }
        }
      }
    }
  }
  __syncthreads();
  if (t < 64) topidx[b * 64 + t] = (int)(s[t] & 0xFFFFFFFFull);
}

// sort 128 selected features ascending, final leaky, write
__global__ void emit1(const float* __restrict__ h1, const int* __restrict__ topidx, float* __restrict__ out){
  __shared__ float s[128];
  int b = blockIdx.x >> 6, k = blockIdx.x & 63;
  int t = threadIdx.x;            // 128
  int nloc = topidx[b * 64 + k];
  s[t] = h1[((size_t)b * NPG_ + nloc) * 128 + t];
  for (int k2 = 2; k2 <= 128; k2 <<= 1){
    for (int j = k2 >> 1; j > 0; j >>= 1){
      __syncthreads();
      int p = t ^ j;
      if (p > t){
        float A = s[t], C = s[p];
        bool up = ((t & k2) == 0);
        if ((A > C) == up){ s[t] = C; s[p] = A; }
      }
    }
  }
  __syncthreads();
  out[(size_t)b * OUT_ROW + (size_t)k * 128 + t] = lrelu(s[t]);
}

// ---------------- layer 2 ----------------
// h2p[n][c] = rsq_out[n] * dot(h1[n][0:128], W2[:,c])  (W2: [128,32] row-major)
__global__ void proj2(const float* __restrict__ h1, const float* __restrict__ W2,
                      const float* __restrict__ rsq_out, float* __restrict__ h2p){
  __shared__ float w[128 * 32];   // 16 KB
  __shared__ float a[16][128];    // 8 KB
  int t = threadIdx.x;            // 256
  for (int i = t; i < 128 * 32; i += 256) w[i] = W2[i];
  int base = blockIdx.x * 16;
  for (int i = t; i < 16 * 128; i += 256){
    int r = i >> 7, c = i & 127;
    a[r][c] = h1[(size_t)(base + r) * 128 + c];
  }
  __syncthreads();
  int c  = t & 31;
  int r0 = t >> 5;                // 0..7
  for (int rr = r0; rr < 16; rr += 8){
    float acc = 0.f;
    #pragma unroll
    for (int k = 0; k < 128; ++k) acc += a[rr][k] * w[k * 32 + c];
    int node = base + rr;
    h2p[(size_t)node * 32 + c] = acc * rsq_out[node];
  }
}

// h2c[v][c] = rsq_in[v] * sum_e csr_w * h2p[src][c]
__global__ void spmm2(const int* __restrict__ off, const int* __restrict__ cnt,
                      const int* __restrict__ csr_src, const float* __restrict__ csr_w,
                      const float* __restrict__ rsq_in, const float* __restrict__ h2p,
                      float* __restrict__ h2c){
  int tid  = blockIdx.x * 256 + threadIdx.x;
  int node = tid >> 5;
  int sl   = tid & 31;
  if (node >= TOTAL_N_) return;
  int s0 = off[node];
  int n  = cnt[node];
  float acc = 0.f;
  int e = 0;
  for (; e + 1 < n; e += 2){
    int sA = csr_src[s0 + e], sB = csr_src[s0 + e + 1];
    acc += csr_w[s0 + e]     * h2p[(size_t)sA * 32 + sl];
    acc += csr_w[s0 + e + 1] * h2p[(size_t)sB * 32 + sl];
  }
  if (e < n){
    int sA = csr_src[s0 + e];
    acc += csr_w[s0 + e] * h2p[(size_t)sA * 32 + sl];
  }
  h2c[(size_t)node * 32 + sl] = acc * rsq_in[node];
}

__global__ void stats2(const float* __restrict__ h, float* __restrict__ gsum, float* __restrict__ gsq){
  int b = blockIdx.x / 25, chunk = blockIdx.x % 25;
  int t = threadIdx.x;
  int c = t & 31, r0 = t >> 5;
  size_t base = ((size_t)b * NPG_ + (size_t)chunk * 500) * 32;
  float s = 0.f, q = 0.f;
  for (int r = r0; r < 500; r += 8){
    float v = h[base + (size_t)r * 32 + c];
    s += v; q += v * v;
  }
  __shared__ float ls[256], lq[256];
  ls[t] = s; lq[t] = q;
  __syncthreads();
  if (t < 32){
    float S = 0.f, Q = 0.f;
    for (int i = 0; i < 8; ++i){ S += ls[t + 32 * i]; Q += lq[t + 32 * i]; }
    atomicAdd(&gsum[b * 32 + t], S);
    atomicAdd(&gsq [b * 32 + t], Q);
  }
}

__global__ void finalize2(const float* __restrict__ gsum, const float* __restrict__ gsq,
                          const float* __restrict__ gamma, const float* __restrict__ beta,
                          const float* __restrict__ alpha, float* __restrict__ mul, float* __restrict__ add){
  int i = threadIdx.x;            // 256 = 8*32
  int c = i & 31;
  const float invn = 1.0f / (float)NPG_;
  float m = gsum[i] * invn;
  float a = alpha[c];
  float var = gsq[i] * invn - 2.f * a * m * m + a * a * m * m;
  float mu = gamma[c] * rsqrtf(var + 1e-5f);
  mul[i] = mu;
  add[i] = beta[c] - mu * a * m;
}

__global__ void norm2(float* __restrict__ h, const float* __restrict__ mul, const float* __restrict__ add,
                      unsigned long long* __restrict__ keys){
  int tid  = blockIdx.x * 256 + threadIdx.x;
  int node = tid >> 5;
  int sl   = tid & 31;
  if (node >= TOTAL_N_) return;
  int b = node / NPG_;
  int nloc = node - b * NPG_;
  float v = h[(size_t)node * 32 + sl];
  v = lrelu(mul[b * 32 + sl] * v + add[b * 32 + sl]);
  h[(size_t)node * 32 + sl] = v;
  float m = v;
  for (int o = 1; o < 32; o <<= 1) m = fmaxf(m, __shfl_xor(m, o));
  if (sl == 0){
    unsigned u = __float_as_uint(m);
    u ^= (u >> 31) ? 0xFFFFFFFFu : 0x80000000u;
    unsigned k32 = ~u;
    keys[(size_t)b * NKEY_ + nloc] = ((unsigned long long)k32 << 32) | (unsigned)nloc;
  }
}

// sort 32 selected features ascending within wave (shfl bitonic), final leaky, write
__global__ void emit2(const float* __restrict__ h2, const int* __restrict__ topidx, float* __restrict__ out){
  int b = blockIdx.x >> 6, k = blockIdx.x & 63;
  int lane = threadIdx.x;         // 32
  int nloc = topidx[b * 64 + k];
  float v = h2[((size_t)b * NPG_ + nloc) * 32 + lane];
  for (int k2 = 2; k2 <= 32; k2 <<= 1){
    for (int j = k2 >> 1; j > 0; j >>= 1){
      float o = __shfl_xor(v, j);
      bool up    = ((lane & k2) == 0);
      bool lower = ((lane & j) == 0);
      v = (up == lower) ? fminf(v, o) : fmaxf(v, o);
    }
  }
  out[(size_t)b * OUT_ROW + 8192 + (size_t)k * 32 + lane] = lrelu(v);
}

__global__ void sentinel_kernel(float* out){
  int i = blockIdx.x * 256 + threadIdx.x;
  if (i < B_ * OUT_ROW) out[i] = -777.0f;
}

extern "C" void kernel_launch(void* const* d_in, const int* in_sizes, int n_in,
                              void* d_out, int out_size, void* d_ws, size_t ws_size,
                              hipStream_t stream){
  const float* feat   = (const float*)d_in[0];
  const float* ew     = (const float*)d_in[1];
  const float* W1     = (const float*)d_in[2];
  const float* W2     = (const float*)d_in[3];
  const float* gamma1 = (const float*)d_in[4];
  const float* beta1  = (const float*)d_in[5];
  const float* alpha1 = (const float*)d_in[6];
  const float* gamma2 = (const float*)d_in[7];
  const float* beta2  = (const float*)d_in[8];
  const float* alpha2 = (const float*)d_in[9];
  const int*   esrc   = (const int*)d_in[10];
  const int*   edst   = (const int*)d_in[11];
  float* out = (float*)d_out;

  char* ws = (char*)d_ws;
  auto alloc = [&](size_t bytes) -> char* {
    char* p = ws;
    ws += (bytes + 255) & ~(size_t)255;
    return p;
  };

  // zeroed region (must stay first & contiguous)
  int*   in_cnt  = (int*)  alloc((size_t)TOTAL_N_ * 4);
  int*   out_cnt = (int*)  alloc((size_t)TOTAL_N_ * 4);
  int*   cursor  = (int*)  alloc((size_t)TOTAL_N_ * 4);
  float* gsum1   = (float*)alloc(1024 * 4);
  float* gsq1    = (float*)alloc(1024 * 4);
  float* gsum2   = (float*)alloc(256 * 4);
  float* gsq2    = (float*)alloc(256 * 4);
  size_t zero_bytes = (size_t)(ws - (char*)d_ws);

  float* rsq_in  = (float*)alloc((size_t)TOTAL_N_ * 4);
  float* rsq_out = (float*)alloc((size_t)TOTAL_N_ * 4);
  int*   off     = (int*)  alloc((size_t)TOTAL_N_ * 4);
  int*   bsum    = (int*)  alloc(512 * 4);
  float* mul1    = (float*)alloc(1024 * 4);
  float* add1    = (float*)alloc(1024 * 4);
  float* mul2    = (float*)alloc(256 * 4);
  float* add2    = (float*)alloc(256 * 4);
  int*   topidx1 = (int*)  alloc(512 * 4);
  int*   topidx2 = (int*)  alloc(512 * 4);
  unsigned long long* cand = (unsigned long long*)alloc((size_t)B_ * 512 * 8);
  unsigned long long* keys = (unsigned long long*)alloc((size_t)B_ * NKEY_ * 8);
  int*   csr_src = (int*)  alloc((size_t)TOTAL_E_ * 4);
  float* csr_w   = (float*)alloc((size_t)TOTAL_E_ * 4);
  float* h2p     = (float*)alloc((size_t)TOTAL_N_ * 32 * 4);
  float* h2c     = (float*)alloc((size_t)TOTAL_N_ * 32 * 4);
  float* agg     = (float*)alloc((size_t)TOTAL_N_ * 64 * 4);
  float* h1      = (float*)alloc((size_t)TOTAL_N_ * 128 * 4);

  size_t need = (size_t)(ws - (char*)d_ws);
  if (need > ws_size){
    sentinel_kernel<<<(B_ * OUT_ROW + 255) / 256, 256, 0, stream>>>(out);
    return;
  }

  hipMemsetAsync(d_ws, 0, zero_bytes, stream);
  hipMemsetAsync(keys, 0xFF, (size_t)B_ * NKEY_ * 8, stream);

  deg_kernel <<<(TOTAL_E_ + 255) / 256, 256, 0, stream>>>(esrc, edst, out_cnt, in_cnt);
  rsq_kernel <<<NB_SCAN, 256, 0, stream>>>(in_cnt, out_cnt, rsq_in, rsq_out);
  scan_blocks<<<NB_SCAN, 256, 0, stream>>>(in_cnt, off, bsum);
  scan_sums  <<<1, 512, 0, stream>>>(bsum, NB_SCAN);
  scan_add   <<<NB_SCAN, 256, 0, stream>>>(off, bsum);
  fill_csr   <<<(TOTAL_E_ + 255) / 256, 256, 0, stream>>>(esrc, edst, ew, off, cursor, csr_src, csr_w);

  // layer 1
  spmm1   <<<TOTAL_N_ * 64 / 256, 256, 0, stream>>>(off, in_cnt, csr_src, csr_w, rsq_out, feat, agg);
  proj1   <<<TOTAL_N_ / 32, 256, 0, stream>>>(agg, W1, rsq_in, h1);
  stats1  <<<200, 256, 0, stream>>>(h1, gsum1, gsq1);
  finalize1<<<1, 1024, 0, stream>>>(gsum1, gsq1, gamma1, beta1, alpha1, mul1, add1);
  norm1   <<<TOTAL_N_ * 64 / 256, 256, 0, stream>>>(h1, mul1, add1, keys);
  topk_s1 <<<B_ * 8, 256, 0, stream>>>(keys, cand);
  topk_s2 <<<B_, 256, 0, stream>>>(cand, topidx1);
  emit1   <<<B_ * 64, 128, 0, stream>>>(h1, topidx1, out);

  // layer 2
  proj2   <<<TOTAL_N_ / 16, 256, 0, stream>>>(h1, W2, rsq_out, h2p);
  spmm2   <<<TOTAL_N_ * 32 / 256, 256, 0, stream>>>(off, in_cnt, csr_src, csr_w, rsq_in, h2p, h2c);
  stats2  <<<200, 256, 0, stream>>>(h2c, gsum2, gsq2);
  finalize2<<<1, 256, 0, stream>>>(gsum2, gsq2, gamma2, beta2, alpha2, mul2, add2);
  norm2   <<<TOTAL_N_ * 32 / 256, 256, 0, stream>>>(h2c, mul2, add2, keys);
  topk_s1 <<<B_ * 8, 256, 0, stream>>>(keys, cand);
  topk_s2 <<<B_, 256, 0, stream>>>(cand, topidx2);
  emit2   <<<B_ * 64, 32, 0, stream>>>(h2c, topidx2, out);
}